// Round 5
// baseline (64.541 us; speedup 1.0000x reference)
//
#include <hip/hip_runtime.h>
#include <hip/hip_bf16.h>

constexpr int KST  = 12;
constexpr int NN   = 10;
constexpr int B    = 2;
constexpr int C    = 512;
constexpr int T    = 4096;
constexpr int BAND = 12;

typedef float f32x4  __attribute__((ext_vector_type(4)));
typedef short bf16x8 __attribute__((ext_vector_type(8)));
typedef unsigned short u16x8 __attribute__((ext_vector_type(8)));

__device__ __forceinline__ float logsig(float x) {
    return fminf(x, 0.0f) - log1pf(expf(-fabsf(x)));
}
__device__ __forceinline__ unsigned short f2bf(float f) {
    union { float f; unsigned u; } v; v.f = f;
    unsigned r = v.u + 0x7fff + ((v.u >> 16) & 1);   // RNE
    return (unsigned short)(r >> 16);
}

// ---------------------------------------------------------------------------
// Kernel 0: cast W fp32 -> bf16 (row-major kept: Wh[d][k])
// ---------------------------------------------------------------------------
__global__ __launch_bounds__(256) void cast_w(
    const float* __restrict__ W, unsigned short* __restrict__ Wh)
{
    const int i = (blockIdx.x * 256 + threadIdx.x) * 4;
    const float4 v = *(const float4*)&W[i];
    short4 o;
    o.x = (short)f2bf(v.x);
    o.y = (short)f2bf(v.y);
    o.z = (short)f2bf(v.z);
    o.w = (short)f2bf(v.w);
    *(short4*)&Wh[i] = o;
}

// ---------------------------------------------------------------------------
// Kernel 1: transpose-cast  X[b][c][t] fp32 -> XT[b][t][c] bf16.
// 64x64 tiles through padded LDS; both global sides coalesced.
// grid (T/64, C/64, 4): z: 0,1 = fc b=0,1 ; 2,3 = enc b=0,1
// ---------------------------------------------------------------------------
__global__ __launch_bounds__(256) void prep_transpose(
    const float* __restrict__ fc, const float* __restrict__ enc,
    unsigned short* __restrict__ fcT, unsigned short* __restrict__ encT)
{
    const int z  = blockIdx.z;
    const float* src = (z < 2 ? fc : enc) + (size_t)(z & 1) * C * T;
    unsigned short* dst = (z < 2 ? fcT : encT) + (size_t)(z & 1) * T * C;
    const int t0 = blockIdx.x * 64;
    const int c0 = blockIdx.y * 64;

    __shared__ float lt[64][65];   // [t][c], pad -> 2-way banks (free)

    const int tid = threadIdx.x;
    // read: 4 passes, each pass: 16 c-rows x 64 t (fully coalesced 256B rows)
    const int tq = (tid & 15) * 4;
    const int cr = tid >> 4;           // 0..15
    #pragma unroll
    for (int p = 0; p < 4; ++p) {
        const int c_row = p * 16 + cr;
        const float4 v = *(const float4*)&src[(size_t)(c0 + c_row) * T + t0 + tq];
        lt[tq + 0][c_row] = v.x;
        lt[tq + 1][c_row] = v.y;
        lt[tq + 2][c_row] = v.z;
        lt[tq + 3][c_row] = v.w;
    }
    __syncthreads();

    // write: thread -> (t_row = tid/4, c-chunk of 16) ; 32B stores
    const int t_row = tid >> 2;
    const int cq    = (tid & 3) * 16;
    u16x8 o0, o1;
    #pragma unroll
    for (int u = 0; u < 8; ++u) o0[u] = f2bf(lt[t_row][cq + u]);
    #pragma unroll
    for (int u = 0; u < 8; ++u) o1[u] = f2bf(lt[t_row][cq + 8 + u]);
    unsigned short* dp = dst + (size_t)(t0 + t_row) * C + c0 + cq;
    *(u16x8*)dp       = o0;
    *(u16x8*)(dp + 8) = o1;
}

// ---------------------------------------------------------------------------
// Kernel 2: fused GEMM + band. Per (32-col s-tile, batch), 8 waves:
//  Stage A: c[d][s-tile] = W @ fc + b. Wave w: d in [w*64, w*64+64).
//    A-frags: Wh rows (global, L2-resident). B-frags: fcT rows (global).
//    4 m-frags x 2 n-frags x 16 ksteps, NO LDS, NO barriers.
//  Epi A : c frags + bias -> bf16 -> swizzled LDS c_t[s=32][d=512].
//  Stage B: D[64 x 32] = encT-rows x c_t^T. Diagonals k=row-col in [0,12)
//    -> logsig -> reduce -> atomicAdd ; rows 44..53 -> negls[b][n][s].
// Swizzle: elem (row, x) at byte row*1024 + (((x>>3) ^ (row&7))<<4) + (x&7)*2
// ---------------------------------------------------------------------------
__global__ __launch_bounds__(512) void fused_kernel(
    const unsigned short* __restrict__ Wh, const unsigned short* __restrict__ fcT,
    const unsigned short* __restrict__ encT, const float* __restrict__ bias,
    float* __restrict__ negls, float* __restrict__ out)
{
    const int b  = blockIdx.y;
    const int n0 = blockIdx.x * 32;

    __shared__ unsigned short c_t[32 * 512];
    __shared__ float posred[8];

    const int tid  = threadIdx.x;
    const int lane = tid & 63;
    const int w    = tid >> 6;       // 0..7
    const int l15  = lane & 15;
    const int l4   = lane >> 4;      // 0..3
    const int mw   = w * 64;

    const unsigned short* fcTb  = fcT  + (size_t)b * T * C;
    const unsigned short* encTb = encT + (size_t)b * T * C;

    // ---------------- stage A: pure-register GEMM ----------------
    f32x4 acc[4][2] = {};
    const unsigned short* Ab  = Wh   + (size_t)(mw + l15) * C + l4 * 8;
    const unsigned short* Bb0 = fcTb + (size_t)(n0 + l15) * C + l4 * 8;
    const unsigned short* Bb1 = Bb0 + 16 * C;

    #pragma unroll 4
    for (int ks = 0; ks < 16; ++ks) {
        const int ko = ks * 32;
        const bf16x8 b0 = *(const bf16x8*)(Bb0 + ko);
        const bf16x8 b1 = *(const bf16x8*)(Bb1 + ko);
        #pragma unroll
        for (int i = 0; i < 4; ++i) {
            const bf16x8 a = *(const bf16x8*)(Ab + (size_t)i * 16 * C + ko);
            acc[i][0] = __builtin_amdgcn_mfma_f32_16x16x32_bf16(a, b0, acc[i][0], 0, 0, 0);
            acc[i][1] = __builtin_amdgcn_mfma_f32_16x16x32_bf16(a, b1, acc[i][1], 0, 0, 0);
        }
    }

    // ---------------- epilogue A: c frags -> swizzled c_t ----------------
    #pragma unroll
    for (int i = 0; i < 4; ++i) {
        const int mb = mw + i * 16 + l4 * 4;     // d base (mult of 4)
        const float4 bv = *(const float4*)&bias[mb];
        const int g = mb >> 3;
        #pragma unroll
        for (int j = 0; j < 2; ++j) {
            const int sp = j * 16 + l15;
            ushort4 u;
            u.x = f2bf(acc[i][j][0] + bv.x);
            u.y = f2bf(acc[i][j][1] + bv.y);
            u.z = f2bf(acc[i][j][2] + bv.z);
            u.w = f2bf(acc[i][j][3] + bv.w);
            const int off = sp * 1024 + ((g ^ (sp & 7)) << 4) + ((mb & 4) << 1);
            *(ushort4*)((char*)c_t + off) = u;
        }
    }
    __syncthreads();

    // ---------------- stage B: band MFMA ----------------
    const int i2 = w >> 1;               // 0..3 row-frag
    const int j2 = w & 1;                // 0..1 col-frag
    const int rg = i2 * 16 + l15;        // D row 0..63
    int ti;                               // t index of A row
    if (rg < 44) { ti = n0 + rg; ti = ti < T ? ti : T - 1; }
    else if (rg < 54) ti = rg - 44;
    else ti = 0;                          // unused rows
    const unsigned short* A2p = encTb + (size_t)ti * C + l4 * 8;
    const char* B2b = (const char*)c_t + (j2 * 16 + l15) * 1024;
    const int bx2 = l15 & 7;

    f32x4 dacc = {};
    #pragma unroll 4
    for (int ks = 0; ks < 16; ++ks) {
        const bf16x8 a2 = *(const bf16x8*)(A2p + ks * 32);
        const int ga = ks * 4 + l4;
        const bf16x8 b2 = *(const bf16x8*)(B2b + ((ga ^ bx2) << 4));
        dacc = __builtin_amdgcn_mfma_f32_16x16x32_bf16(a2, b2, dacc, 0, 0, 0);
    }

    // ---------------- epilogue B ----------------
    float pos = 0.0f;
    const int colr = j2 * 16 + l15;
    const int scol = n0 + colr;
    #pragma unroll
    for (int r = 0; r < 4; ++r) {
        const int row = i2 * 16 + l4 * 4 + r;
        const float vv = dacc[r];
        if (row < 44) {
            const int k = row - colr;
            if (k >= 0 && k < BAND && scol + k < T) pos += logsig(vv);
        } else if (row < 54) {
            negls[((size_t)b * NN + (row - 44)) * T + scol] = logsig(-vv);
        }
    }
    #pragma unroll
    for (int off = 32; off > 0; off >>= 1) pos += __shfl_down(pos, off, 64);
    if (lane == 0) posred[w] = pos;
    __syncthreads();
    if (tid == 0) {
        float tsum = 0.0f;
        #pragma unroll
        for (int q = 0; q < 8; ++q) tsum += posred[q];
        atomicAdd(out, tsum);
    }
}

// ---------------------------------------------------------------------------
// Kernel 3: gather negatives; out += NN * sum logsig(-cont[b,n,idx]).
// ---------------------------------------------------------------------------
__global__ __launch_bounds__(256) void gather_kernel(
    const int4* __restrict__ nidx4, const float* __restrict__ negls,
    float* __restrict__ out)
{
    const int i4 = blockIdx.x * 256 + threadIdx.x;
    const int4 vv = nidx4[i4];
    const int base = i4 * 4;
    const int idxs[4] = {vv.x, vv.y, vv.z, vv.w};
    float local = 0.0f;
    #pragma unroll
    for (int e = 0; e < 4; ++e) {
        const int n = (base + e) % NN;     // layout [k][t][n], n fastest
        local += negls[(size_t)n * T + idxs[e]]
               + negls[(size_t)(NN + n) * T + idxs[e]];
    }
    #pragma unroll
    for (int off = 32; off > 0; off >>= 1) local += __shfl_down(local, off, 64);
    __shared__ float wsum[4];
    if ((threadIdx.x & 63) == 0) wsum[threadIdx.x >> 6] = local;
    __syncthreads();
    if (threadIdx.x == 0)
        atomicAdd(out, (float)NN * (wsum[0] + wsum[1] + wsum[2] + wsum[3]));
}

// ---------------------------------------------------------------------------
extern "C" void kernel_launch(void* const* d_in, const int* in_sizes, int n_in,
                              void* d_out, int out_size, void* d_ws, size_t ws_size,
                              hipStream_t stream)
{
    const float* enc  = (const float*)d_in[0];
    const float* fc   = (const float*)d_in[1];
    const float* W    = (const float*)d_in[2];
    const float* bias = (const float*)d_in[3];
    const int*   nidx = (const int*)d_in[4];
    float* out = (float*)d_out;

    unsigned short* fcT  = (unsigned short*)d_ws;                 // B*T*C bf16 (8 MiB)
    unsigned short* encT = fcT + (size_t)B * T * C;               // 8 MiB
    unsigned short* Wh   = encT + (size_t)B * T * C;              // 512 KiB
    float* negls = (float*)(Wh + (size_t)C * C);                  // 320 KiB

    hipMemsetAsync(out, 0, sizeof(float), stream);

    cast_w<<<C * C / (256 * 4), 256, 0, stream>>>(W, Wh);
    prep_transpose<<<dim3(T / 64, C / 64, 4), 256, 0, stream>>>(fc, enc, fcT, encT);
    fused_kernel<<<dim3(T / 32, B), 512, 0, stream>>>(Wh, fcT, encT, bias, negls, out);
    gather_kernel<<<KST * T * NN / (4 * 256), 256, 0, stream>>>(
        (const int4*)nidx, negls, out);
}